// Round 5
// baseline (113.108 us; speedup 1.0000x reference)
//
#include <hip/hip_runtime.h>
#include <math.h>

#define UNITS 1024
#define FEAT  1024
#define GATES 4096   // 4*UNITS

// ws layout (float offsets)
#define OFF_Z0  0                 // z0  = b + x0@W
#define OFF_Z1X (GATES)           // z1x = b + x1@W
#define OFF_Z1  (2*GATES)         // z1  = z1x + h0@U
#define OFF_CNT (3*GATES)         // int done-counter (reset by k_xw)

__device__ __forceinline__ float sigmoidf(float x) { return 1.0f / (1.0f + expf(-x)); }

// XCD-aware swizzle: each XCD owns 512 contiguous columns.
__device__ __forceinline__ int col_group(int bx) {
    return ((bx & 7) << 5) + (bx >> 3);
}

// K1: 256 blocks, each computes 16 full-depth columns of BOTH x0@W and x1@W,
// writing z0 and z1x directly. Also resets the done-counter for K2.
__global__ __launch_bounds__(256) void k_xw(const float* __restrict__ x,
                                            const float* __restrict__ W,
                                            const float* __restrict__ b,
                                            float* __restrict__ ws) {
    int tid = threadIdx.x;
    int c0 = col_group(blockIdx.x) * 16;
    if (blockIdx.x == 0 && tid == 0) *reinterpret_cast<int*>(ws + OFF_CNT) = 0;

    __shared__ float xs0[FEAT], xs1[FEAT];
    {
        float4 v0 = *reinterpret_cast<const float4*>(&x[tid * 4]);
        float4 v1 = *reinterpret_cast<const float4*>(&x[FEAT + tid * 4]);
        *reinterpret_cast<float4*>(&xs0[tid * 4]) = v0;
        *reinterpret_cast<float4*>(&xs1[tid * 4]) = v1;
    }
    __syncthreads();

    int q = tid & 3;
    int rowbase = tid >> 2;           // 0..63
    const float* wp = W + (size_t)rowbase * GATES + c0 + q * 4;
    float4 a0 = make_float4(0.f, 0.f, 0.f, 0.f);
    float4 a1 = make_float4(0.f, 0.f, 0.f, 0.f);
#pragma unroll
    for (int it = 0; it < 16; ++it) {
        int row = it * 64 + rowbase;
        float4 w = *reinterpret_cast<const float4*>(wp + (size_t)it * 64 * GATES);
        float x0 = xs0[row], x1 = xs1[row];
        a0.x += x0 * w.x; a0.y += x0 * w.y; a0.z += x0 * w.z; a0.w += x0 * w.w;
        a1.x += x1 * w.x; a1.y += x1 * w.y; a1.z += x1 * w.z; a1.w += x1 * w.w;
    }
#pragma unroll
    for (int s = 32; s >= 4; s >>= 1) {
        a0.x += __shfl_down(a0.x, s); a0.y += __shfl_down(a0.y, s);
        a0.z += __shfl_down(a0.z, s); a0.w += __shfl_down(a0.w, s);
        a1.x += __shfl_down(a1.x, s); a1.y += __shfl_down(a1.y, s);
        a1.z += __shfl_down(a1.z, s); a1.w += __shfl_down(a1.w, s);
    }
    __shared__ float4 p0[4][4], p1[4][4];   // [wave][q]
    int wave = tid >> 6, lane = tid & 63;
    if (lane < 4) { p0[wave][lane] = a0; p1[wave][lane] = a1; }
    __syncthreads();
    if (tid < 4) {
        float4 s0 = p0[0][tid], s1 = p1[0][tid];
#pragma unroll
        for (int w = 1; w < 4; ++w) {
            s0.x += p0[w][tid].x; s0.y += p0[w][tid].y; s0.z += p0[w][tid].z; s0.w += p0[w][tid].w;
            s1.x += p1[w][tid].x; s1.y += p1[w][tid].y; s1.z += p1[w][tid].z; s1.w += p1[w][tid].w;
        }
        float4 bb = *reinterpret_cast<const float4*>(&b[c0 + tid * 4]);
        s0.x += bb.x; s0.y += bb.y; s0.z += bb.z; s0.w += bb.w;
        s1.x += bb.x; s1.y += bb.y; s1.z += bb.z; s1.w += bb.w;
        *reinterpret_cast<float4*>(&ws[OFF_Z0 + c0 + tid * 4]) = s0;
        *reinterpret_cast<float4*>(&ws[OFF_Z1X + c0 + tid * 4]) = s1;
    }
}

// K2: 256 blocks. Each recomputes all 1024 h0 from z0 into LDS, computes its
// 16 full-depth columns of h0@U, writes z1 = z1x + that. The LAST block to
// finish (device-scope atomic counter) then computes the epilogue in-place.
__global__ __launch_bounds__(256) void k_hu(const float* __restrict__ U,
                                            const float* __restrict__ f,
                                            const float* __restrict__ Wd,
                                            const float* __restrict__ bd,
                                            float* __restrict__ ws,
                                            float* __restrict__ out) {
    int tid = threadIdx.x;
    int c0 = col_group(blockIdx.x) * 16;

    __shared__ float h0s[UNITS];
    {
        int u0 = tid * 4;
        float4 zi = *reinterpret_cast<const float4*>(&ws[OFF_Z0 + u0]);
        float4 zg = *reinterpret_cast<const float4*>(&ws[OFF_Z0 + 2 * UNITS + u0]);
        float4 zo = *reinterpret_cast<const float4*>(&ws[OFF_Z0 + 3 * UNITS + u0]);
        float4 h;
        h.x = sigmoidf(zo.x) * (sigmoidf(zi.x) * zg.x);
        h.y = sigmoidf(zo.y) * (sigmoidf(zi.y) * zg.y);
        h.z = sigmoidf(zo.z) * (sigmoidf(zi.z) * zg.z);
        h.w = sigmoidf(zo.w) * (sigmoidf(zi.w) * zg.w);
        *reinterpret_cast<float4*>(&h0s[u0]) = h;
    }
    __syncthreads();

    int q = tid & 3;
    int rowbase = tid >> 2;
    const float* up = U + (size_t)rowbase * GATES + c0 + q * 4;
    float4 a = make_float4(0.f, 0.f, 0.f, 0.f);
#pragma unroll
    for (int it = 0; it < 16; ++it) {
        int row = it * 64 + rowbase;
        float4 u4 = *reinterpret_cast<const float4*>(up + (size_t)it * 64 * GATES);
        float h = h0s[row];
        a.x += h * u4.x; a.y += h * u4.y; a.z += h * u4.z; a.w += h * u4.w;
    }
#pragma unroll
    for (int s = 32; s >= 4; s >>= 1) {
        a.x += __shfl_down(a.x, s); a.y += __shfl_down(a.y, s);
        a.z += __shfl_down(a.z, s); a.w += __shfl_down(a.w, s);
    }
    __shared__ float4 pu[4][4];
    int wave = tid >> 6, lane = tid & 63;
    if (lane < 4) pu[wave][lane] = a;
    __syncthreads();
    if (tid < 4) {
        float4 s = pu[0][tid];
#pragma unroll
        for (int w = 1; w < 4; ++w) {
            s.x += pu[w][tid].x; s.y += pu[w][tid].y; s.z += pu[w][tid].z; s.w += pu[w][tid].w;
        }
        float4 zx = *reinterpret_cast<const float4*>(&ws[OFF_Z1X + c0 + tid * 4]);
        s.x += zx.x; s.y += zx.y; s.z += zx.z; s.w += zx.w;
        *reinterpret_cast<float4*>(&ws[OFF_Z1 + c0 + tid * 4]) = s;
    }

    // --- last-block-done epilogue ---
    __shared__ int slast;
    __syncthreads();
    if (tid == 0) {
        __threadfence();  // release this block's z1 stores
        int old = atomicAdd(reinterpret_cast<int*>(ws + OFF_CNT), 1);
        slast = (old == 255);
    }
    __syncthreads();
    if (!slast) return;
    __threadfence();      // acquire: see all blocks' z1 stores

    const float* Z0 = ws + OFF_Z0;
    const float* Z1 = ws + OFF_Z1;
    float4 v = make_float4(0.f, 0.f, 0.f, 0.f);
#pragma unroll
    for (int i = 0; i < 4; ++i) {
        int u = tid + i * 256;
        float cc0 = sigmoidf(Z0[u]) * Z0[u + 2 * UNITS];
        float h0 = sigmoidf(Z0[u + 3 * UNITS]) * cc0;
        float c1 = sigmoidf(Z1[u + UNITS]) * cc0 + sigmoidf(Z1[u]) * Z1[u + 2 * UNITS];
        float h1 = sigmoidf(Z1[u + 3 * UNITS]) * c1;
        float n0 = tanhf(h0);
        float n1 = tanhf(h1);
        float2 wd = *reinterpret_cast<const float2*>(&Wd[2 * u]);
        v.x += n0 * wd.x; v.y += n0 * wd.y;
        v.z += n1 * wd.x; v.w += n1 * wd.y;
    }
#pragma unroll
    for (int s = 32; s > 0; s >>= 1) {
        v.x += __shfl_down(v.x, s);
        v.y += __shfl_down(v.y, s);
        v.z += __shfl_down(v.z, s);
        v.w += __shfl_down(v.w, s);
    }
    __shared__ float4 wred[4];
    if (lane == 0) wred[wave] = v;
    __syncthreads();
    if (tid == 0) {
        float4 sa = wred[0];
#pragma unroll
        for (int w = 1; w < 4; ++w) {
            float4 t = wred[w];
            sa.x += t.x; sa.y += t.y; sa.z += t.z; sa.w += t.w;
        }
        float hc00 = tanhf(sa.x + bd[0]);
        float hc01 = tanhf(sa.y + bd[1]);
        float hc10 = tanhf(sa.z + bd[0]);
        float hc11 = tanhf(sa.w + bd[1]);
        float den = f[1] - f[2];
        out[0] = hc00;
        out[1] = hc01;
        out[2] = (hc00 - hc10) / den;
        out[3] = (hc01 - hc11) / den;
    }
}

extern "C" void kernel_launch(void* const* d_in, const int* in_sizes, int n_in,
                              void* d_out, int out_size, void* d_ws, size_t ws_size,
                              hipStream_t stream) {
    const float* x  = (const float*)d_in[0];  // (1, 8192, 1024) — only rows 0,1 used
    const float* f  = (const float*)d_in[1];  // (8192, 1)
    const float* W  = (const float*)d_in[2];  // (1024, 4096)
    const float* U  = (const float*)d_in[3];  // (1024, 4096)
    const float* b  = (const float*)d_in[4];  // (4096,)
    const float* Wd = (const float*)d_in[5];  // (1024, 2)
    const float* bd = (const float*)d_in[6];  // (2,)
    float* out = (float*)d_out;               // 4 floats
    float* ws  = (float*)d_ws;                // ~48 KB scratch used

    k_xw<<<256, 256, 0, stream>>>(x, W, b, ws);
    k_hu<<<256, 256, 0, stream>>>(U, f, Wd, bd, ws, out);
}

// Round 6
// 105.494 us; speedup vs baseline: 1.0722x; 1.0722x over previous
//
#include <hip/hip_runtime.h>
#include <math.h>

#define UNITS 1024
#define FEAT  1024
#define GATES 4096   // 4*UNITS

// ws layout (float offsets) — no partials, just the three 4096-vectors
#define OFF_Z0  0                 // z0  = b + x0@W
#define OFF_Z1X (GATES)           // z1x = b + x1@W
#define OFF_Z1  (2*GATES)         // z1  = z1x + h0@U

__device__ __forceinline__ float sigmoidf(float x) { return 1.0f / (1.0f + expf(-x)); }

// Column-group for a block: XCD-aware swizzle (bx%8 = XCD heuristic) so each
// XCD owns 32 consecutive 16-col groups = 512 contiguous columns.
__device__ __forceinline__ int col_group(int bx) {
    return ((bx & 7) << 5) + (bx >> 3);
}

// K1: 256 blocks, each computes 16 full-depth columns of BOTH x0@W and x1@W,
// writing z0 and z1x directly. W read exactly once, no partials, no atomics.
__global__ __launch_bounds__(256) void k_xw(const float* __restrict__ x,
                                            const float* __restrict__ W,
                                            const float* __restrict__ b,
                                            float* __restrict__ ws) {
    int tid = threadIdx.x;
    int c0 = col_group(blockIdx.x) * 16;

    __shared__ float xs0[FEAT], xs1[FEAT];
    {
        float4 v0 = *reinterpret_cast<const float4*>(&x[tid * 4]);
        float4 v1 = *reinterpret_cast<const float4*>(&x[FEAT + tid * 4]);
        *reinterpret_cast<float4*>(&xs0[tid * 4]) = v0;
        *reinterpret_cast<float4*>(&xs1[tid * 4]) = v1;
    }
    __syncthreads();

    int q = tid & 3;
    int rowbase = tid >> 2;           // 0..63
    const float* wp = W + (size_t)rowbase * GATES + c0 + q * 4;
    float4 a0 = make_float4(0.f, 0.f, 0.f, 0.f);
    float4 a1 = make_float4(0.f, 0.f, 0.f, 0.f);
#pragma unroll
    for (int it = 0; it < 16; ++it) {
        int row = it * 64 + rowbase;
        float4 w = *reinterpret_cast<const float4*>(wp + (size_t)it * 64 * GATES);
        float x0 = xs0[row], x1 = xs1[row];
        a0.x += x0 * w.x; a0.y += x0 * w.y; a0.z += x0 * w.z; a0.w += x0 * w.w;
        a1.x += x1 * w.x; a1.y += x1 * w.y; a1.z += x1 * w.z; a1.w += x1 * w.w;
    }
    // reduce across rowbase (stride-4 lanes share q)
#pragma unroll
    for (int s = 32; s >= 4; s >>= 1) {
        a0.x += __shfl_down(a0.x, s); a0.y += __shfl_down(a0.y, s);
        a0.z += __shfl_down(a0.z, s); a0.w += __shfl_down(a0.w, s);
        a1.x += __shfl_down(a1.x, s); a1.y += __shfl_down(a1.y, s);
        a1.z += __shfl_down(a1.z, s); a1.w += __shfl_down(a1.w, s);
    }
    __shared__ float4 p0[4][4], p1[4][4];   // [wave][q]
    int wave = tid >> 6, lane = tid & 63;
    if (lane < 4) { p0[wave][lane] = a0; p1[wave][lane] = a1; }
    __syncthreads();
    if (tid < 4) {
        float4 s0 = p0[0][tid], s1 = p1[0][tid];
#pragma unroll
        for (int w = 1; w < 4; ++w) {
            s0.x += p0[w][tid].x; s0.y += p0[w][tid].y; s0.z += p0[w][tid].z; s0.w += p0[w][tid].w;
            s1.x += p1[w][tid].x; s1.y += p1[w][tid].y; s1.z += p1[w][tid].z; s1.w += p1[w][tid].w;
        }
        float4 bb = *reinterpret_cast<const float4*>(&b[c0 + tid * 4]);
        s0.x += bb.x; s0.y += bb.y; s0.z += bb.z; s0.w += bb.w;
        s1.x += bb.x; s1.y += bb.y; s1.z += bb.z; s1.w += bb.w;
        *reinterpret_cast<float4*>(&ws[OFF_Z0 + c0 + tid * 4]) = s0;
        *reinterpret_cast<float4*>(&ws[OFF_Z1X + c0 + tid * 4]) = s1;
    }
}

// K2: 256 blocks, each recomputes all 1024 h0 from z0 (12 KB, L2-hot) into LDS,
// then computes 16 full-depth columns of h0@U and writes z1 = z1x + that.
__global__ __launch_bounds__(256) void k_hu(const float* __restrict__ U,
                                            float* __restrict__ ws) {
    int tid = threadIdx.x;
    int c0 = col_group(blockIdx.x) * 16;

    __shared__ float h0s[UNITS];
    {
        int u0 = tid * 4;
        float4 zi = *reinterpret_cast<const float4*>(&ws[OFF_Z0 + u0]);
        float4 zg = *reinterpret_cast<const float4*>(&ws[OFF_Z0 + 2 * UNITS + u0]);
        float4 zo = *reinterpret_cast<const float4*>(&ws[OFF_Z0 + 3 * UNITS + u0]);
        float4 h;
        h.x = sigmoidf(zo.x) * (sigmoidf(zi.x) * zg.x);
        h.y = sigmoidf(zo.y) * (sigmoidf(zi.y) * zg.y);
        h.z = sigmoidf(zo.z) * (sigmoidf(zi.z) * zg.z);
        h.w = sigmoidf(zo.w) * (sigmoidf(zi.w) * zg.w);
        *reinterpret_cast<float4*>(&h0s[u0]) = h;
    }
    __syncthreads();

    int q = tid & 3;
    int rowbase = tid >> 2;
    const float* up = U + (size_t)rowbase * GATES + c0 + q * 4;
    float4 a = make_float4(0.f, 0.f, 0.f, 0.f);
#pragma unroll
    for (int it = 0; it < 16; ++it) {
        int row = it * 64 + rowbase;
        float4 u4 = *reinterpret_cast<const float4*>(up + (size_t)it * 64 * GATES);
        float h = h0s[row];
        a.x += h * u4.x; a.y += h * u4.y; a.z += h * u4.z; a.w += h * u4.w;
    }
#pragma unroll
    for (int s = 32; s >= 4; s >>= 1) {
        a.x += __shfl_down(a.x, s); a.y += __shfl_down(a.y, s);
        a.z += __shfl_down(a.z, s); a.w += __shfl_down(a.w, s);
    }
    __shared__ float4 pu[4][4];
    int wave = tid >> 6, lane = tid & 63;
    if (lane < 4) pu[wave][lane] = a;
    __syncthreads();
    if (tid < 4) {
        float4 s = pu[0][tid];
#pragma unroll
        for (int w = 1; w < 4; ++w) {
            s.x += pu[w][tid].x; s.y += pu[w][tid].y; s.z += pu[w][tid].z; s.w += pu[w][tid].w;
        }
        float4 zx = *reinterpret_cast<const float4*>(&ws[OFF_Z1X + c0 + tid * 4]);
        s.x += zx.x; s.y += zx.y; s.z += zx.z; s.w += zx.w;
        *reinterpret_cast<float4*>(&ws[OFF_Z1 + c0 + tid * 4]) = s;
    }
}

// K3: gates for steps 0/1, tanh, dense(2) reduction, outputs. 1 block x 1024.
__global__ __launch_bounds__(1024) void k_final(const float* __restrict__ ws,
                                                const float* __restrict__ f,
                                                const float* __restrict__ Wd,
                                                const float* __restrict__ bd,
                                                float* __restrict__ out) {
    int u = threadIdx.x;  // 0..1023
    const float* Z0 = ws + OFF_Z0;
    const float* Z1 = ws + OFF_Z1;
    float c0 = sigmoidf(Z0[u]) * Z0[u + 2 * UNITS];
    float h0 = sigmoidf(Z0[u + 3 * UNITS]) * c0;
    float c1 = sigmoidf(Z1[u + UNITS]) * c0 + sigmoidf(Z1[u]) * Z1[u + 2 * UNITS];
    float h1 = sigmoidf(Z1[u + 3 * UNITS]) * c1;

    float n0 = tanhf(h0);
    float n1 = tanhf(h1);
    float2 wd = *reinterpret_cast<const float2*>(&Wd[2 * u]);

    float4 v = make_float4(n0 * wd.x, n0 * wd.y, n1 * wd.x, n1 * wd.y);
#pragma unroll
    for (int s = 32; s > 0; s >>= 1) {
        v.x += __shfl_down(v.x, s);
        v.y += __shfl_down(v.y, s);
        v.z += __shfl_down(v.z, s);
        v.w += __shfl_down(v.w, s);
    }
    __shared__ float4 wred[16];
    int wave = u >> 6;
    if ((u & 63) == 0) wred[wave] = v;
    __syncthreads();
    if (u == 0) {
        float4 sa = wred[0];
#pragma unroll
        for (int w = 1; w < 16; ++w) {
            float4 t = wred[w];
            sa.x += t.x; sa.y += t.y; sa.z += t.z; sa.w += t.w;
        }
        float hc00 = tanhf(sa.x + bd[0]);
        float hc01 = tanhf(sa.y + bd[1]);
        float hc10 = tanhf(sa.z + bd[0]);
        float hc11 = tanhf(sa.w + bd[1]);
        float den = f[1] - f[2];
        out[0] = hc00;
        out[1] = hc01;
        out[2] = (hc00 - hc10) / den;
        out[3] = (hc01 - hc11) / den;
    }
}

extern "C" void kernel_launch(void* const* d_in, const int* in_sizes, int n_in,
                              void* d_out, int out_size, void* d_ws, size_t ws_size,
                              hipStream_t stream) {
    const float* x  = (const float*)d_in[0];  // (1, 8192, 1024) — only rows 0,1 used
    const float* f  = (const float*)d_in[1];  // (8192, 1)
    const float* W  = (const float*)d_in[2];  // (1024, 4096)
    const float* U  = (const float*)d_in[3];  // (1024, 4096)
    const float* b  = (const float*)d_in[4];  // (4096,)
    const float* Wd = (const float*)d_in[5];  // (1024, 2)
    const float* bd = (const float*)d_in[6];  // (2,)
    float* out = (float*)d_out;               // 4 floats
    float* ws  = (float*)d_ws;                // 48 KB scratch used

    k_xw   <<<256, 256, 0, stream>>>(x, W, b, ws);
    k_hu   <<<256, 256, 0, stream>>>(U, ws);
    k_final<<<  1, 1024, 0, stream>>>(ws, f, Wd, bd, out);
}